// Round 9
// baseline (204.855 us; speedup 1.0000x reference)
//
#include <hip/hip_runtime.h>
#include <hip/hip_bf16.h>

// Problem constants (B=2, T=2048, D=1024, H=16, hd=64)
#define T_SEQ 2048
#define DM    1024
#define MTOT  4096   // B*T

typedef short v8s __attribute__((ext_vector_type(8)));   // 8 x bf16 (4 VGPRs)
typedef short v4s __attribute__((ext_vector_type(4)));   // 4 x bf16 (2 VGPRs)
typedef float v4f __attribute__((ext_vector_type(4)));   // MFMA accumulator

// fp32 -> bf16 round-to-nearest-even
__device__ __forceinline__ unsigned short f2bf(float f) {
  union { float f; unsigned int u; } x; x.f = f;
  return (unsigned short)((x.u + (((x.u >> 16) & 1u) + 0x7fffu)) >> 16);
}

// fast pack: two fp32 -> packed bf16x2 (round-half-up) via v_perm_b32
__device__ __forceinline__ unsigned int pk2(float a, float b) {
  unsigned int ua = __float_as_uint(a) + 0x8000u;
  unsigned int ub = __float_as_uint(b) + 0x8000u;
  return __builtin_amdgcn_perm(ub, ua, 0x07060302u);  // [ub_hi16, ua_hi16]
}

// pack 8 fp32 (two float4) -> v8s
__device__ __forceinline__ v8s pack8f(float4 a, float4 b) {
  union { v8s s; unsigned int u[4]; } o;
  o.u[0] = pk2(a.x, a.y); o.u[1] = pk2(a.z, a.w);
  o.u[2] = pk2(b.x, b.y); o.u[3] = pk2(b.z, b.w);
  return o.s;
}

// pack two v4f (P^T C-layout regs) -> one v8s B-operand for K=32 PV mfma
__device__ __forceinline__ v8s pack8bf(v4f a, v4f b) {
  union { v8s s; unsigned int u[4]; } o;
  o.u[0] = pk2(a[0], a[1]);
  o.u[1] = pk2(a[2], a[3]);
  o.u[2] = pk2(b[0], b[1]);
  o.u[3] = pk2(b[2], b[3]);
  return o.s;
}

// raw v_exp_f32 (2^x); denormal output flushes to 0 which is what we want
__device__ __forceinline__ float fast_exp2(float x) {
#if __has_builtin(__builtin_amdgcn_exp2f)
  return __builtin_amdgcn_exp2f(x);
#else
  return exp2f(x);
#endif
}

// async global->LDS, 16B per lane: lane i lands at lds + i*16 (wave-uniform base).
__device__ __forceinline__ void gload16(const void* g, void* lds) {
  __builtin_amdgcn_global_load_lds(
      (const __attribute__((address_space(1))) unsigned int*)g,
      (__attribute__((address_space(3))) unsigned int*)lds, 16, 0, 0);
}

// ---------------------------------------------------------------------------
// FUSED QKV v3: reads fp32 x / W directly (inline bf16 conversion during
// staging — convert_all dispatch eliminated; each block only needs its own
// A-tile rows and W rows, no cross-block dependency).
// Tile 128M x 64N, grid (32,16) = 512 = 2/CU. LDS: As 16KB | 3x W 8KB.
// XOR chunk swizzle (slot s of row r holds k-chunk s^(r&7)).
// V epilogue: permuted panel Vt[((bh*16+tblk)*64 + d)*128 + p].
// ---------------------------------------------------------------------------
__global__ __launch_bounds__(256) void qkv_fused3(
    const float* __restrict__ x,
    const float* __restrict__ Wq, const float* __restrict__ Wk,
    const float* __restrict__ Wv,
    unsigned short* __restrict__ Qw, unsigned short* __restrict__ Kw,
    unsigned short* __restrict__ Vtw)
{
  __shared__ unsigned short smem[20480];   // 40KB
  unsigned short* As = smem;               // [128][64]

  const int tid  = threadIdx.x;
  const int wv   = tid >> 6, l = tid & 63;
  const int lrow = l & 15, lq = l >> 4;
  const int wm = wv >> 1;        // m-half (64 rows)
  const int wn = wv & 1;         // n-half (32 cols)
  const int srow = l >> 3, sslot = l & 7;
  const int swz  = sslot ^ (srow & 7);
  const int m0 = blockIdx.x * 128, n0 = blockIdx.y * 64;

  v4f acc[3][4][2];
#pragma unroll
  for (int z = 0; z < 3; ++z)
#pragma unroll
    for (int mt = 0; mt < 4; ++mt)
#pragma unroll
      for (int nt = 0; nt < 2; ++nt) acc[z][mt][nt] = (v4f){0.f, 0.f, 0.f, 0.f};

  // fp32 source bases (element offsets)
  const size_t aBase = (size_t)(m0 + wv * 32 + srow) * DM + swz * 8;
  const size_t bBase = (size_t)(n0 + wv * 16 + srow) * DM + swz * 8;
  const float* Wz[3] = { Wq, Wk, Wv };

  for (int k0 = 0; k0 < DM; k0 += 64) {
    __syncthreads();
    // A: 4 chunks/thread (rows wv*32 + i*8 + srow), 8 fp32 -> 8 bf16 each
#pragma unroll
    for (int i = 0; i < 4; ++i) {
      const float* src = x + aBase + (size_t)i * 8 * DM + k0;
      float4 f0 = *(const float4*)src;
      float4 f1 = *(const float4*)(src + 4);
      *(v8s*)&As[(wv * 32 + i * 8 + srow) * 64 + sslot * 8] = pack8f(f0, f1);
    }
    // W: 2 chunks/thread per z (rows wv*16 + i*8 + srow)
#pragma unroll
    for (int z = 0; z < 3; ++z)
#pragma unroll
      for (int i = 0; i < 2; ++i) {
        const float* src = Wz[z] + bBase + (size_t)i * 8 * DM + k0;
        float4 f0 = *(const float4*)src;
        float4 f1 = *(const float4*)(src + 4);
        *(v8s*)&smem[8192 + z * 4096 + (wv * 16 + i * 8 + srow) * 64 + sslot * 8] =
            pack8f(f0, f1);
      }
    __syncthreads();
#pragma unroll
    for (int kc = 0; kc < 2; ++kc) {
      const int aslot = ((kc << 2) | lq) ^ (lrow & 7);
      v8s af[4];
#pragma unroll
      for (int mt = 0; mt < 4; ++mt)
        af[mt] = *(const v8s*)&As[(wm * 64 + mt * 16 + lrow) * 64 + aslot * 8];
#pragma unroll
      for (int z = 0; z < 3; ++z) {
        const unsigned short* Bz = smem + 8192 + z * 4096;
        v8s bf[2];
#pragma unroll
        for (int nt = 0; nt < 2; ++nt)
          bf[nt] = *(const v8s*)&Bz[(wn * 32 + nt * 16 + lrow) * 64 + aslot * 8];
#pragma unroll
        for (int mt = 0; mt < 4; ++mt)
#pragma unroll
          for (int nt = 0; nt < 2; ++nt)
            acc[z][mt][nt] = __builtin_amdgcn_mfma_f32_16x16x32_bf16(
                af[mt], bf[nt], acc[z][mt][nt], 0, 0, 0);
      }
    }
  }

  // Q and K: direct row-major stores
#pragma unroll
  for (int z = 0; z < 2; ++z) {
    unsigned short* Y = z ? Kw : Qw;
#pragma unroll
    for (int mt = 0; mt < 4; ++mt)
#pragma unroll
      for (int nt = 0; nt < 2; ++nt)
#pragma unroll
        for (int r = 0; r < 4; ++r) {
          int row = m0 + wm * 64 + mt * 16 + lq * 4 + r;
          int col = n0 + wn * 32 + nt * 16 + lrow;
          Y[(size_t)row * DM + col] = f2bf(acc[z][mt][nt][r]);
        }
  }

  // V: stage C-tile [128 t][64 d] swizzled in LDS, then b128 permuted panel
  __syncthreads();   // K-loop LDS reads done
#pragma unroll
  for (int mt = 0; mt < 4; ++mt)
#pragma unroll
    for (int nt = 0; nt < 2; ++nt)
#pragma unroll
      for (int r = 0; r < 4; ++r) {
        int trow = wm * 64 + mt * 16 + lq * 4 + r;     // 0..127 (token)
        int col  = wn * 32 + nt * 16 + lrow;           // 0..63  (d)
        int slot = (col >> 3) ^ (trow & 7);
        smem[trow * 64 + slot * 8 + (col & 7)] = f2bf(acc[2][mt][nt][r]);
      }
  __syncthreads();
  {
    const int d = tid & 63;
    const int quarter = tid >> 6;        // 32-key group
    const int bb = m0 >> 11;
    const int tblk = (m0 & 2047) >> 7;
    const int h = n0 >> 6;
    const int bh = bb * 16 + h;
    unsigned short* dst = Vtw + (((size_t)bh * 16 + tblk) * 64 + d) * 128;
    const int ch = d >> 3, e7 = d & 7;
#pragma unroll
    for (int jj = 0; jj < 4; ++jj) {
      unsigned short vals[8];
#pragma unroll
      for (int e = 0; e < 8; ++e) {
        int st = quarter * 32 + (e >> 2) * 16 + jj * 4 + (e & 3);  // source key
        vals[e] = smem[st * 64 + (ch ^ (st & 7)) * 8 + e7];
      }
      *(v8s*)(dst + (quarter * 4 + jj) * 8) = *(const v8s*)vals;
    }
  }
}

// ---------------------------------------------------------------------------
// Output projection v3: AO bf16 via gload16; Wo fp32 with inline conversion.
// Tile 64M x 128N, grid (64,8) = 512 = 2/CU. fp32 out.
// ---------------------------------------------------------------------------
__global__ __launch_bounds__(256) void oproj_gemm3(
    const unsigned short* __restrict__ AO,
    const float* __restrict__ Wo,
    float* __restrict__ Y)
{
  __shared__ unsigned short smem[12288];   // 24KB
  unsigned short* As = smem;               // [64][64]
  unsigned short* Bs = smem + 4096;        // [128][64]

  const int tid  = threadIdx.x;
  const int wv   = tid >> 6, l = tid & 63;
  const int lrow = l & 15, lq = l >> 4;
  const int wm = wv >> 1;
  const int wn = wv & 1;
  const int srow = l >> 3, sslot = l & 7;
  const int swz  = sslot ^ (srow & 7);
  const int m0 = blockIdx.x * 64, n0 = blockIdx.y * 128;

  v4f acc[2][4];
#pragma unroll
  for (int mt = 0; mt < 2; ++mt)
#pragma unroll
    for (int nt = 0; nt < 4; ++nt) acc[mt][nt] = (v4f){0.f, 0.f, 0.f, 0.f};

  const size_t aBase = (size_t)(m0 + wv * 16 + srow) * DM + swz * 8;
  const size_t bBase = (size_t)(n0 + wv * 32 + srow) * DM + swz * 8;

  for (int k0 = 0; k0 < DM; k0 += 64) {
    __syncthreads();
#pragma unroll
    for (int i = 0; i < 2; ++i)
      gload16(AO + aBase + (size_t)i * 8 * DM + k0, As + (wv * 16 + i * 8) * 64);
#pragma unroll
    for (int i = 0; i < 4; ++i) {
      const float* src = Wo + bBase + (size_t)i * 8 * DM + k0;
      float4 f0 = *(const float4*)src;
      float4 f1 = *(const float4*)(src + 4);
      *(v8s*)&Bs[(wv * 32 + i * 8 + srow) * 64 + sslot * 8] = pack8f(f0, f1);
    }
    __syncthreads();
#pragma unroll
    for (int kc = 0; kc < 2; ++kc) {
      const int aslot = ((kc << 2) | lq) ^ (lrow & 7);
      v8s af[2], bf[4];
#pragma unroll
      for (int mt = 0; mt < 2; ++mt)
        af[mt] = *(const v8s*)&As[(wm * 32 + mt * 16 + lrow) * 64 + aslot * 8];
#pragma unroll
      for (int nt = 0; nt < 4; ++nt)
        bf[nt] = *(const v8s*)&Bs[(wn * 64 + nt * 16 + lrow) * 64 + aslot * 8];
#pragma unroll
      for (int mt = 0; mt < 2; ++mt)
#pragma unroll
        for (int nt = 0; nt < 4; ++nt)
          acc[mt][nt] = __builtin_amdgcn_mfma_f32_16x16x32_bf16(
              af[mt], bf[nt], acc[mt][nt], 0, 0, 0);
    }
  }
#pragma unroll
  for (int mt = 0; mt < 2; ++mt)
#pragma unroll
    for (int nt = 0; nt < 4; ++nt)
#pragma unroll
      for (int r = 0; r < 4; ++r) {
        int row = m0 + wm * 32 + mt * 16 + lq * 4 + r;
        int col = n0 + wn * 64 + nt * 16 + lrow;
        Y[(size_t)row * DM + col] = acc[mt][nt][r];
      }
}

// ---------------------------------------------------------------------------
// Flash attention v6 (R8-proven): transposed-S, register-resident P, MFMA
// row-sums (A=ones), fixed-base softmax. LDS 32KB.
// ---------------------------------------------------------------------------
__global__ __launch_bounds__(256) void attn6(
    const unsigned short* __restrict__ Q,
    const unsigned short* __restrict__ K,
    const unsigned short* __restrict__ Vt,
    unsigned short* __restrict__ O)
{
  __shared__ unsigned short Ks[128 * 64];   // [key][d chunk swz]        16KB
  __shared__ unsigned short Vts[64 * 128];  // [d][key-permuted chunk]   16KB

  const int tid  = threadIdx.x;
  const int wave = tid >> 6;
  const int lane = tid & 63;
  const int lrow = lane & 15;
  const int lq   = lane >> 4;
  const int gid  = blockIdx.x;
  const int qt   = 31 - (gid >> 5);   // LPT: longest first
  const int bh   = gid & 31;
  const int b = bh >> 4, h = bh & 15;

  // ones bf16 A-operand for the row-sum mfma
  union { v8s s; unsigned int u[4]; } ones;
  ones.u[0] = 0x3F803F80u; ones.u[1] = 0x3F803F80u;
  ones.u[2] = 0x3F803F80u; ones.u[3] = 0x3F803F80u;

  // Q fragment = B-operand of S^T mfma: n=q=lrow, k=d=lq*8+j
  const int qrow = qt * 64 + wave * 16 + lrow;
  const unsigned short* qp = Q + ((size_t)(b * T_SEQ + qrow)) * DM + h * 64;
  v8s qf0 = *(const v8s*)(qp + lq * 8);
  v8s qf1 = *(const v8s*)(qp + 32 + lq * 8);

  v4f oacc[4];
#pragma unroll
  for (int dt = 0; dt < 4; ++dt) oacc[dt] = (v4f){0.f, 0.f, 0.f, 0.f};
  v4f sacc = {0.f, 0.f, 0.f, 0.f};

  const int nkt = (qt >> 1) + 1;

  const int kchunk = (lane & 7) ^ ((lane >> 3) & 7);
  const unsigned short* kg =
      K + ((size_t)(b * T_SEQ) + wave * 8 + (lane >> 3)) * DM + h * 64 + kchunk * 8;
  unsigned short* kdst = Ks + (wave * 8) * 64;
  const int vd = wave * 4 + (lane >> 4);
  const int vslot = lane & 15;
  const int vchunk = (vslot & 8) | ((vslot & 7) ^ (vd & 7));
  const unsigned short* vg =
      Vt + ((size_t)bh * 1024 + vd) * 128 + vchunk * 8;
  unsigned short* vdst = Vts + (wave * 4) * 128;

  for (int kt = 0; kt < nkt; ++kt) {
    __syncthreads();
#pragma unroll
    for (int i = 0; i < 4; ++i)
      gload16(kg + ((size_t)kt * 128 + i * 32) * DM, kdst + i * 32 * 64);
#pragma unroll
    for (int i = 0; i < 4; ++i)
      gload16(vg + (size_t)kt * 8192 + i * 2048, vdst + i * 16 * 128);
    __syncthreads();

    // S^T = K Q^T : A = K frag (m=key, k=d), B = Q frag
    v4f s[8];
    const int slot0 = lq ^ (lrow & 7);
    const int slot1 = (4 + lq) ^ (lrow & 7);
#pragma unroll
    for (int nt = 0; nt < 8; ++nt) {
      v4f a = {0.f, 0.f, 0.f, 0.f};
      v8s k0 = *(const v8s*)&Ks[(nt * 16 + lrow) * 64 + slot0 * 8];
      a = __builtin_amdgcn_mfma_f32_16x16x32_bf16(k0, qf0, a, 0, 0, 0);
      v8s k1 = *(const v8s*)&Ks[(nt * 16 + lrow) * 64 + slot1 * 8];
      a = __builtin_amdgcn_mfma_f32_16x16x32_bf16(k1, qf1, a, 0, 0, 0);
      s[nt] = a;
    }

    // p = exp2(s*0.125*log2e - 16*log2e); causal mask on last tile only.
    // s[nt][r] holds S^T[key = kt*128 + nt*16 + lq*4 + r][q = lrow]
    const bool lastt = (kt == nkt - 1);
    if (lastt) {
#pragma unroll
      for (int nt = 0; nt < 8; ++nt)
#pragma unroll
        for (int r = 0; r < 4; ++r) {
          float p = fast_exp2(fmaf(s[nt][r], 0.18033688f, -23.0831206f));
          if (kt * 128 + nt * 16 + lq * 4 + r > qt * 64 + wave * 16 + lrow) p = 0.f;
          s[nt][r] = p;
        }
    } else {
#pragma unroll
      for (int nt = 0; nt < 8; ++nt)
#pragma unroll
        for (int r = 0; r < 4; ++r)
          s[nt][r] = fast_exp2(fmaf(s[nt][r], 0.18033688f, -23.0831206f));
    }

    // P^T stays in registers: pack pairs of 16-key blocks into K=32 B-operands
    v8s pf[4];
#pragma unroll
    for (int kp = 0; kp < 4; ++kp) pf[kp] = pack8bf(s[2 * kp], s[2 * kp + 1]);

    // O^T += V^T P ; row-sums += ones^T P (matrix pipe does the reduction)
#pragma unroll
    for (int kp = 0; kp < 4; ++kp) {
      sacc = __builtin_amdgcn_mfma_f32_16x16x32_bf16(ones.s, pf[kp], sacc, 0, 0, 0);
#pragma unroll
      for (int dt = 0; dt < 4; ++dt) {
        int ch = kp * 4 + lq;
        int slot = (ch & 8) | ((ch & 7) ^ (lrow & 7));
        v8s vv = *(const v8s*)&Vts[(dt * 16 + lrow) * 128 + slot * 8];
        oacc[dt] = __builtin_amdgcn_mfma_f32_16x16x32_bf16(
            vv, pf[kp], oacc[dt], 0, 0, 0);
      }
    }
  }

  // every lane already holds its q's key-sum (all sacc rows identical)
  const float rinv = 1.0f / sacc[0];

  // O^T C-layout: q = lrow, d = dt*16 + lq*4 + r -> b64 packed stores
  const int token = qt * 64 + wave * 16 + lrow;
  unsigned short* op = O + ((size_t)(b * T_SEQ + token)) * DM + h * 64;
#pragma unroll
  for (int dt = 0; dt < 4; ++dt) {
    union { v4s s; unsigned int u[2]; } o;
    o.u[0] = pk2(oacc[dt][0] * rinv, oacc[dt][1] * rinv);
    o.u[1] = pk2(oacc[dt][2] * rinv, oacc[dt][3] * rinv);
    *(v4s*)(op + dt * 16 + lq * 4) = o.s;
  }
}

// ---------------------------------------------------------------------------
extern "C" void kernel_launch(void* const* d_in, const int* in_sizes, int n_in,
                              void* d_out, int out_size, void* d_ws, size_t ws_size,
                              hipStream_t stream) {
  const float* x  = (const float*)d_in[0];
  const float* Wq = (const float*)d_in[1];
  const float* Wk = (const float*)d_in[2];
  const float* Wv = (const float*)d_in[3];
  const float* Wo = (const float*)d_in[4];
  float* out = (float*)d_out;

  unsigned short* Qw  = (unsigned short*)d_ws;
  unsigned short* Kw  = Qw + (size_t)MTOT * DM;
  unsigned short* Vtw = Kw + (size_t)MTOT * DM;
  unsigned short* AO  = Vtw + (size_t)MTOT * DM;

  qkv_fused3<<<dim3(32, 16), 256, 0, stream>>>(x, Wq, Wk, Wv, Qw, Kw, Vtw);
  attn6<<<1024, 256, 0, stream>>>(Qw, Kw, Vtw, AO);
  oproj_gemm3<<<dim3(64, 8), 256, 0, stream>>>(AO, Wo, out);
}

// Round 10
// 163.872 us; speedup vs baseline: 1.2501x; 1.2501x over previous
//
#include <hip/hip_runtime.h>
#include <hip/hip_bf16.h>

// Problem constants (B=2, T=2048, D=1024, H=16, hd=64)
#define T_SEQ 2048
#define DM    1024
#define MTOT  4096   // B*T

typedef short v8s __attribute__((ext_vector_type(8)));   // 8 x bf16 (4 VGPRs)
typedef short v4s __attribute__((ext_vector_type(4)));   // 4 x bf16 (2 VGPRs)
typedef float v4f __attribute__((ext_vector_type(4)));   // MFMA accumulator

// fp32 -> bf16 round-to-nearest-even
__device__ __forceinline__ unsigned short f2bf(float f) {
  union { float f; unsigned int u; } x; x.f = f;
  return (unsigned short)((x.u + (((x.u >> 16) & 1u) + 0x7fffu)) >> 16);
}

// fast pack: two fp32 -> packed bf16x2 (round-half-up) via v_perm_b32
__device__ __forceinline__ unsigned int pk2(float a, float b) {
  unsigned int ua = __float_as_uint(a) + 0x8000u;
  unsigned int ub = __float_as_uint(b) + 0x8000u;
  return __builtin_amdgcn_perm(ub, ua, 0x07060302u);  // [ub_hi16, ua_hi16]
}

// pack two v4f (P^T C-layout regs) -> one v8s B-operand for K=32 PV mfma
__device__ __forceinline__ v8s pack8bf(v4f a, v4f b) {
  union { v8s s; unsigned int u[4]; } o;
  o.u[0] = pk2(a[0], a[1]);
  o.u[1] = pk2(a[2], a[3]);
  o.u[2] = pk2(b[0], b[1]);
  o.u[3] = pk2(b[2], b[3]);
  return o.s;
}

// raw v_exp_f32 (2^x); denormal output flushes to 0 which is what we want
__device__ __forceinline__ float fast_exp2(float x) {
#if __has_builtin(__builtin_amdgcn_exp2f)
  return __builtin_amdgcn_exp2f(x);
#else
  return exp2f(x);
#endif
}

// async global->LDS, 16B per lane: lane i lands at lds + i*16 (wave-uniform base).
__device__ __forceinline__ void gload16(const void* g, void* lds) {
  __builtin_amdgcn_global_load_lds(
      (const __attribute__((address_space(1))) unsigned int*)g,
      (__attribute__((address_space(3))) unsigned int*)lds, 16, 0, 0);
}

// ---------------------------------------------------------------------------
// Convert x + Wq/Wk/Wv/Wo to bf16 in workspace.  (R8-proven)
// ---------------------------------------------------------------------------
__global__ __launch_bounds__(256) void convert_all(
    const float* __restrict__ x,
    const float* __restrict__ Wq, const float* __restrict__ Wk,
    const float* __restrict__ Wv, const float* __restrict__ Wo,
    unsigned short* __restrict__ xb, unsigned short* __restrict__ wb)
{
  int i = blockIdx.x * 256 + threadIdx.x;   // float4 index, 2^21 total
  const float4* src;
  ushort4* dst;
  int idx;
  if (i < (1 << 20)) {
    src = (const float4*)x; dst = (ushort4*)xb; idx = i;
  } else {
    int j = i - (1 << 20);
    int wsel = j >> 18;
    idx = j & ((1 << 18) - 1);
    const float* s = (wsel == 0) ? Wq : (wsel == 1) ? Wk : (wsel == 2) ? Wv : Wo;
    src = (const float4*)s;
    dst = (ushort4*)(wb + (size_t)wsel * DM * DM);
  }
  float4 v = src[idx];
  ushort4 o = { f2bf(v.x), f2bf(v.y), f2bf(v.z), f2bf(v.w) };
  dst[idx] = o;
}

// ---------------------------------------------------------------------------
// FUSED QKV (R8-proven): tile 128M x 64N, grid (32,16) = 512 = 2/CU.
// LDS: As 16KB | Wq 8KB | Wk 8KB | Wv 8KB. XOR chunk swizzle.
// V epilogue: permuted panel Vt[((bh*16+tblk)*64 + d)*128 + p].
// ---------------------------------------------------------------------------
__global__ __launch_bounds__(256) void qkv_fused2(
    const unsigned short* __restrict__ xb,
    const unsigned short* __restrict__ wb,
    unsigned short* __restrict__ Qw, unsigned short* __restrict__ Kw,
    unsigned short* __restrict__ Vtw)
{
  __shared__ unsigned short smem[20480];   // 40KB
  unsigned short* As = smem;               // [128][64]

  const int tid  = threadIdx.x;
  const int wv   = tid >> 6, l = tid & 63;
  const int lrow = l & 15, lq = l >> 4;
  const int wm = wv >> 1;        // m-half (64 rows)
  const int wn = wv & 1;         // n-half (32 cols)
  const int srow = l >> 3, sslot = l & 7;
  const int swz  = sslot ^ (srow & 7);
  const int m0 = blockIdx.x * 128, n0 = blockIdx.y * 64;

  v4f acc[3][4][2];
#pragma unroll
  for (int z = 0; z < 3; ++z)
#pragma unroll
    for (int mt = 0; mt < 4; ++mt)
#pragma unroll
      for (int nt = 0; nt < 2; ++nt) acc[z][mt][nt] = (v4f){0.f, 0.f, 0.f, 0.f};

  const size_t aBase = (size_t)(m0 + wv * 32 + srow) * DM + swz * 8;
  const size_t bBase = (size_t)(n0 + wv * 16 + srow) * DM + swz * 8;

  for (int k0 = 0; k0 < DM; k0 += 64) {
    __syncthreads();
#pragma unroll
    for (int i = 0; i < 4; ++i)
      gload16(xb + aBase + (size_t)i * 8 * DM + k0, As + (wv * 32 + i * 8) * 64);
#pragma unroll
    for (int z = 0; z < 3; ++z)
#pragma unroll
      for (int i = 0; i < 2; ++i)
        gload16(wb + (size_t)z * DM * DM + bBase + (size_t)i * 8 * DM + k0,
                smem + 8192 + z * 4096 + (wv * 16 + i * 8) * 64);
    __syncthreads();
#pragma unroll
    for (int kc = 0; kc < 2; ++kc) {
      const int aslot = ((kc << 2) | lq) ^ (lrow & 7);
      v8s af[4];
#pragma unroll
      for (int mt = 0; mt < 4; ++mt)
        af[mt] = *(const v8s*)&As[(wm * 64 + mt * 16 + lrow) * 64 + aslot * 8];
#pragma unroll
      for (int z = 0; z < 3; ++z) {
        const unsigned short* Bz = smem + 8192 + z * 4096;
        v8s bf[2];
#pragma unroll
        for (int nt = 0; nt < 2; ++nt)
          bf[nt] = *(const v8s*)&Bz[(wn * 32 + nt * 16 + lrow) * 64 + aslot * 8];
#pragma unroll
        for (int mt = 0; mt < 4; ++mt)
#pragma unroll
          for (int nt = 0; nt < 2; ++nt)
            acc[z][mt][nt] = __builtin_amdgcn_mfma_f32_16x16x32_bf16(
                af[mt], bf[nt], acc[z][mt][nt], 0, 0, 0);
      }
    }
  }

  // Q and K: direct row-major stores
#pragma unroll
  for (int z = 0; z < 2; ++z) {
    unsigned short* Y = z ? Kw : Qw;
#pragma unroll
    for (int mt = 0; mt < 4; ++mt)
#pragma unroll
      for (int nt = 0; nt < 2; ++nt)
#pragma unroll
        for (int r = 0; r < 4; ++r) {
          int row = m0 + wm * 64 + mt * 16 + lq * 4 + r;
          int col = n0 + wn * 32 + nt * 16 + lrow;
          Y[(size_t)row * DM + col] = f2bf(acc[z][mt][nt][r]);
        }
  }

  // V: stage C-tile [128 t][64 d] swizzled in LDS, then b128 permuted panel
  __syncthreads();   // K-loop LDS reads done
#pragma unroll
  for (int mt = 0; mt < 4; ++mt)
#pragma unroll
    for (int nt = 0; nt < 2; ++nt)
#pragma unroll
      for (int r = 0; r < 4; ++r) {
        int trow = wm * 64 + mt * 16 + lq * 4 + r;     // 0..127 (token)
        int col  = wn * 32 + nt * 16 + lrow;           // 0..63  (d)
        int slot = (col >> 3) ^ (trow & 7);
        smem[trow * 64 + slot * 8 + (col & 7)] = f2bf(acc[2][mt][nt][r]);
      }
  __syncthreads();
  {
    const int d = tid & 63;
    const int quarter = tid >> 6;        // 32-key group
    const int bb = m0 >> 11;
    const int tblk = (m0 & 2047) >> 7;
    const int h = n0 >> 6;
    const int bh = bb * 16 + h;
    unsigned short* dst = Vtw + (((size_t)bh * 16 + tblk) * 64 + d) * 128;
    const int ch = d >> 3, e7 = d & 7;
#pragma unroll
    for (int jj = 0; jj < 4; ++jj) {
      unsigned short vals[8];
#pragma unroll
      for (int e = 0; e < 8; ++e) {
        int st = quarter * 32 + (e >> 2) * 16 + jj * 4 + (e & 3);  // source key
        vals[e] = smem[st * 64 + (ch ^ (st & 7)) * 8 + e7];
      }
      *(v8s*)(dst + (quarter * 4 + jj) * 8) = *(const v8s*)vals;
    }
  }
}

// ---------------------------------------------------------------------------
// Output projection (R8-proven): tile 64M x 128N, grid (64,8) = 512 = 2/CU.
// ---------------------------------------------------------------------------
__global__ __launch_bounds__(256) void oproj_gemm2(
    const unsigned short* __restrict__ AO,
    const unsigned short* __restrict__ Wob,
    float* __restrict__ Y)
{
  __shared__ unsigned short smem[12288];   // 24KB
  unsigned short* As = smem;               // [64][64]
  unsigned short* Bs = smem + 4096;        // [128][64]

  const int tid  = threadIdx.x;
  const int wv   = tid >> 6, l = tid & 63;
  const int lrow = l & 15, lq = l >> 4;
  const int wm = wv >> 1;
  const int wn = wv & 1;
  const int srow = l >> 3, sslot = l & 7;
  const int swz  = sslot ^ (srow & 7);
  const int m0 = blockIdx.x * 64, n0 = blockIdx.y * 128;

  v4f acc[2][4];
#pragma unroll
  for (int mt = 0; mt < 2; ++mt)
#pragma unroll
    for (int nt = 0; nt < 4; ++nt) acc[mt][nt] = (v4f){0.f, 0.f, 0.f, 0.f};

  const size_t aBase = (size_t)(m0 + wv * 16 + srow) * DM + swz * 8;
  const size_t bBase = (size_t)(n0 + wv * 32 + srow) * DM + swz * 8;

  for (int k0 = 0; k0 < DM; k0 += 64) {
    __syncthreads();
#pragma unroll
    for (int i = 0; i < 2; ++i)
      gload16(AO + aBase + (size_t)i * 8 * DM + k0, As + (wv * 16 + i * 8) * 64);
#pragma unroll
    for (int i = 0; i < 4; ++i)
      gload16(Wob + bBase + (size_t)i * 8 * DM + k0, Bs + (wv * 32 + i * 8) * 64);
    __syncthreads();
#pragma unroll
    for (int kc = 0; kc < 2; ++kc) {
      const int aslot = ((kc << 2) | lq) ^ (lrow & 7);
      v8s af[2], bf[4];
#pragma unroll
      for (int mt = 0; mt < 2; ++mt)
        af[mt] = *(const v8s*)&As[(wm * 32 + mt * 16 + lrow) * 64 + aslot * 8];
#pragma unroll
      for (int nt = 0; nt < 4; ++nt)
        bf[nt] = *(const v8s*)&Bs[(wn * 64 + nt * 16 + lrow) * 64 + aslot * 8];
#pragma unroll
      for (int mt = 0; mt < 2; ++mt)
#pragma unroll
        for (int nt = 0; nt < 4; ++nt)
          acc[mt][nt] = __builtin_amdgcn_mfma_f32_16x16x32_bf16(
              af[mt], bf[nt], acc[mt][nt], 0, 0, 0);
    }
  }
#pragma unroll
  for (int mt = 0; mt < 2; ++mt)
#pragma unroll
    for (int nt = 0; nt < 4; ++nt)
#pragma unroll
      for (int r = 0; r < 4; ++r) {
        int row = m0 + wm * 32 + mt * 16 + lq * 4 + r;
        int col = n0 + wn * 64 + nt * 16 + lrow;
        Y[(size_t)row * DM + col] = acc[mt][nt][r];
      }
}

// ---------------------------------------------------------------------------
// Flash attention v7: attn6 body (transposed-S, register P, MFMA row-sums)
// but KT=256 per barrier-pair as two 128-key sub-tiles. Halves the barrier
// count; a sub-tile whose key-base exceeds the block's max q-row is skipped.
// LDS: Ks[256][64] 32KB + VtsA/VtsB 16KB each = 64KB -> 2 blocks/CU.
// ---------------------------------------------------------------------------
__global__ __launch_bounds__(256) void attn7(
    const unsigned short* __restrict__ Q,
    const unsigned short* __restrict__ K,
    const unsigned short* __restrict__ Vt,
    unsigned short* __restrict__ O)
{
  __shared__ unsigned short Ks[256 * 64];    // [key][d chunk swz]       32KB
  __shared__ unsigned short VtsA[64 * 128];  // [d][key-perm chunk]      16KB
  __shared__ unsigned short VtsB[64 * 128];  // second 128-key panel     16KB

  const int tid  = threadIdx.x;
  const int wave = tid >> 6;
  const int lane = tid & 63;
  const int lrow = lane & 15;
  const int lq   = lane >> 4;
  const int gid  = blockIdx.x;
  const int qt   = 31 - (gid >> 5);   // LPT: longest first
  const int bh   = gid & 31;
  const int b = bh >> 4, h = bh & 15;

  // ones bf16 A-operand for the row-sum mfma
  union { v8s s; unsigned int u[4]; } ones;
  ones.u[0] = 0x3F803F80u; ones.u[1] = 0x3F803F80u;
  ones.u[2] = 0x3F803F80u; ones.u[3] = 0x3F803F80u;

  // Q fragment = B-operand of S^T mfma: n=q=lrow, k=d=lq*8+j
  const int qrow = qt * 64 + wave * 16 + lrow;
  const unsigned short* qp = Q + ((size_t)(b * T_SEQ + qrow)) * DM + h * 64;
  v8s qf0 = *(const v8s*)(qp + lq * 8);
  v8s qf1 = *(const v8s*)(qp + 32 + lq * 8);

  v4f oacc[4];
#pragma unroll
  for (int dt = 0; dt < 4; ++dt) oacc[dt] = (v4f){0.f, 0.f, 0.f, 0.f};
  v4f sacc = {0.f, 0.f, 0.f, 0.f};

  const int nkt = (qt >> 2) + 1;          // 256-key iterations
  const int qmax = qt * 64 + 63;          // block's last q row

  const int kchunk = (lane & 7) ^ ((lane >> 3) & 7);
  const unsigned short* kg =
      K + ((size_t)(b * T_SEQ) + wave * 8 + (lane >> 3)) * DM + h * 64 + kchunk * 8;
  unsigned short* kdst = Ks + (wave * 8) * 64;
  const int vd = wave * 4 + (lane >> 4);
  const int vslot = lane & 15;
  const int vchunk = (vslot & 8) | ((vslot & 7) ^ (vd & 7));
  const unsigned short* vg =
      Vt + ((size_t)bh * 1024 + vd) * 128 + vchunk * 8;
  unsigned short* vdstA = VtsA + (wave * 4) * 128;
  unsigned short* vdstB = VtsB + (wave * 4) * 128;

  const int slot0 = lq ^ (lrow & 7);
  const int slot1 = (4 + lq) ^ (lrow & 7);

  for (int kt = 0; kt < nkt; ++kt) {
    __syncthreads();
    // K: 256 rows (8 gload16/thread)
#pragma unroll
    for (int i = 0; i < 8; ++i)
      gload16(kg + ((size_t)kt * 256 + i * 32) * DM, kdst + i * 32 * 64);
    // V: two 128-key panels (4 gload16 each)
#pragma unroll
    for (int i = 0; i < 4; ++i)
      gload16(vg + (size_t)kt * 16384 + i * 2048, vdstA + i * 16 * 128);
#pragma unroll
    for (int i = 0; i < 4; ++i)
      gload16(vg + (size_t)kt * 16384 + 8192 + i * 2048, vdstB + i * 16 * 128);
    __syncthreads();

#pragma unroll
    for (int sub = 0; sub < 2; ++sub) {
      const int kb = kt * 256 + sub * 128;
      if (kb > qmax) break;   // fully-masked sub-tile (block-uniform)
      const unsigned short* Kss = Ks + sub * 128 * 64;
      const unsigned short* Vts = sub ? VtsB : VtsA;

      // S^T = K Q^T : A = K frag (m=key, k=d), B = Q frag
      v4f s[8];
#pragma unroll
      for (int nt = 0; nt < 8; ++nt) {
        v4f a = {0.f, 0.f, 0.f, 0.f};
        v8s k0 = *(const v8s*)&Kss[(nt * 16 + lrow) * 64 + slot0 * 8];
        a = __builtin_amdgcn_mfma_f32_16x16x32_bf16(k0, qf0, a, 0, 0, 0);
        v8s k1 = *(const v8s*)&Kss[(nt * 16 + lrow) * 64 + slot1 * 8];
        a = __builtin_amdgcn_mfma_f32_16x16x32_bf16(k1, qf1, a, 0, 0, 0);
        s[nt] = a;
      }

      // p = exp2(s*0.125*log2e - 16*log2e); mask only when tile crosses diag
      const bool needmask = (kb + 127 > qt * 64 + wave * 16);
      if (needmask) {
#pragma unroll
        for (int nt = 0; nt < 8; ++nt)
#pragma unroll
          for (int r = 0; r < 4; ++r) {
            float p = fast_exp2(fmaf(s[nt][r], 0.18033688f, -23.0831206f));
            if (kb + nt * 16 + lq * 4 + r > qt * 64 + wave * 16 + lrow) p = 0.f;
            s[nt][r] = p;
          }
      } else {
#pragma unroll
        for (int nt = 0; nt < 8; ++nt)
#pragma unroll
          for (int r = 0; r < 4; ++r)
            s[nt][r] = fast_exp2(fmaf(s[nt][r], 0.18033688f, -23.0831206f));
      }

      // P^T stays in registers: pack into K=32 B-operands
      v8s pf[4];
#pragma unroll
      for (int kp = 0; kp < 4; ++kp) pf[kp] = pack8bf(s[2 * kp], s[2 * kp + 1]);

      // O^T += V^T P ; row-sums += ones^T P
#pragma unroll
      for (int kp = 0; kp < 4; ++kp) {
        sacc = __builtin_amdgcn_mfma_f32_16x16x32_bf16(ones.s, pf[kp], sacc, 0, 0, 0);
#pragma unroll
        for (int dt = 0; dt < 4; ++dt) {
          int ch = kp * 4 + lq;
          int slot = (ch & 8) | ((ch & 7) ^ (lrow & 7));
          v8s vv = *(const v8s*)&Vts[(dt * 16 + lrow) * 128 + slot * 8];
          oacc[dt] = __builtin_amdgcn_mfma_f32_16x16x32_bf16(
              vv, pf[kp], oacc[dt], 0, 0, 0);
        }
      }
    }
  }

  // every lane already holds its q's key-sum (all sacc rows identical)
  const float rinv = 1.0f / sacc[0];

  // O^T C-layout: q = lrow, d = dt*16 + lq*4 + r -> b64 packed stores
  const int token = qt * 64 + wave * 16 + lrow;
  unsigned short* op = O + ((size_t)(b * T_SEQ + token)) * DM + h * 64;
#pragma unroll
  for (int dt = 0; dt < 4; ++dt) {
    union { v4s s; unsigned int u[2]; } o;
    o.u[0] = pk2(oacc[dt][0] * rinv, oacc[dt][1] * rinv);
    o.u[1] = pk2(oacc[dt][2] * rinv, oacc[dt][3] * rinv);
    *(v4s*)(op + dt * 16 + lq * 4) = o.s;
  }
}

// ---------------------------------------------------------------------------
extern "C" void kernel_launch(void* const* d_in, const int* in_sizes, int n_in,
                              void* d_out, int out_size, void* d_ws, size_t ws_size,
                              hipStream_t stream) {
  const float* x  = (const float*)d_in[0];
  const float* Wq = (const float*)d_in[1];
  const float* Wk = (const float*)d_in[2];
  const float* Wv = (const float*)d_in[3];
  const float* Wo = (const float*)d_in[4];
  float* out = (float*)d_out;

  unsigned short* xb  = (unsigned short*)d_ws;
  unsigned short* wb  = xb + (size_t)MTOT * DM;
  unsigned short* Qw  = wb + (size_t)4 * DM * DM;
  unsigned short* Kw  = Qw + (size_t)MTOT * DM;
  unsigned short* Vtw = Kw + (size_t)MTOT * DM;
  unsigned short* AO  = xb;   // xb dead after qkv_fused2 -> reuse

  convert_all<<<8192, 256, 0, stream>>>(x, Wq, Wk, Wv, Wo, xb, wb);
  qkv_fused2<<<dim3(32, 16), 256, 0, stream>>>(xb, wb, Qw, Kw, Vtw);
  attn7<<<1024, 256, 0, stream>>>(Qw, Kw, Vtw, AO);
  oproj_gemm2<<<dim3(64, 8), 256, 0, stream>>>(AO, wb + (size_t)3 * DM * DM, out);
}